// Round 11
// baseline (94.309 us; speedup 1.0000x reference)
//
#include <hip/hip_runtime.h>

#define NB 64
#define NN 1500
#define NM 100
#define NBINS 1280
#define KEEP 128

#define DELTA_FLOATS 31104000u   // floats in delta section; /4 = 7776000 quads
#define ROWS_PER_BLK 64
#define K2_BLOCKS 1500           // 96000 rows / 64

// ws: 0 enc[96000] int | 384000 d4[96000] float4   (total 1,920,000 B)
// enc: -1 = untouched row; 0 = negative (one-hot label 0); 0x100|lab = positive

// ---------------- K1: per-batch IoU + eager delta + barrier-light top-128 select ----------------
__global__ __launch_bounds__(256) void k1_select(
    const float4* __restrict__ roi, const float4* __restrict__ gt,
    const int* __restrict__ gtl, const int* __restrict__ rpos,
    const int* __restrict__ rneg,
    int* __restrict__ enc, float4* __restrict__ d4)
{
    __shared__ float4 gtb[NM];
    __shared__ float  gta[NM];
    __shared__ int    gtlL[NM];
    __shared__ short  sc[2][NN];         // masked scores (0 = not candidate)
    __shared__ short  labS[NN];          // gt label for pos-eligible rows
    __shared__ unsigned char kp[2][NN];
    __shared__ int    hist[NBINS];
    __shared__ int    waveTot[4];
    __shared__ int    cnt6[6][4];
    __shared__ int    sstar_s, q_s;

    int b = blockIdx.x;
    int tid = threadIdx.x;
    int lane = tid & 63, w = tid >> 6;

    if (tid < NM) {
        float4 g = gt[b*NM + tid];
        gtb[tid] = g;
        gta[tid] = (g.z - g.x) * (g.w - g.y);
        gtlL[tid] = gtl[b*NM + tid];
    }
    __syncthreads();

    // ---- IoU + argmax + masked scores + eager delta (to global d4) ----
    for (int c = 0; c < 6; ++c) {
        int n = c*256 + tid;
        if (n < NN) {
            int idx = b*NN + n;
            float4 r = roi[idx];                   // [y1,x1,y2,x2]
            float by1=r.x, bx1=r.y, by2=r.z, bx2=r.w;
            float barea = (by2-by1)*(bx2-bx1);
            float bestIoU = -1.0f; int bestIdx = 0;
            for (int m = 0; m < NM; ++m) {
                float4 g = gtb[m];
                float xt = fmaxf(bx1, g.y);
                float yt = fmaxf(by1, g.x);
                float xb = fminf(bx2, g.w);
                float yb = fminf(by2, g.z);
                float inter = fmaxf(xb-xt, 0.0f) * fmaxf(yb-yt, 0.0f);
                float uni = (barea + gta[m]) - inter;
                float iou = inter / uni;
                if (iou > bestIoU) { bestIoU = iou; bestIdx = m; } // first-max argmax
            }
            sc[0][n] = (short)((bestIoU > 0.5f) ? rpos[idx] : 0);
            sc[1][n] = (short)((bestIoU < 0.5f && bestIoU > 0.1f) ? rneg[idx] : 0);
            labS[n] = 0;
            if (bestIoU > 0.5f) {
                // eager delta for every pos-eligible row (superset of kept set)
                float4 g = gtb[bestIdx];
                float bw = bx2 - bx1, bh = by2 - by1;
                float bcx = bx1 + 0.5f*bw, bcy = by1 + 0.5f*bh;
                float gw = g.w - g.y, gh = g.z - g.x;
                float gcx = g.y + 0.5f*gw, gcy = g.x + 0.5f*gh;
                if (bw == 0.0f) bw = 0.001f;
                if (bh == 0.0f) bh = 0.001f;
                float dx  = (gw==0.0f) ? 0.0f : (gcx-bcx)/bw;
                float dy  = (gh==0.0f) ? 0.0f : (gcy-bcy)/bh;
                float dwv = (gw==0.0f) ? 0.0f : logf(gw/bw);
                float dhv = (gh==0.0f) ? 0.0f : logf(gh/bh);
                d4[idx] = make_float4(dy/0.1f, dx/0.1f, dhv/0.2f, dwv/0.2f);
                labS[n] = (short)gtlL[bestIdx];
            }
        }
    }
    __syncthreads();

    // ---- barrier-light counting top-128 select (R6/R8's passing code) ----
    for (int m = 0; m < 2; ++m) {
        for (int s = tid; s < NBINS; s += 256) hist[s] = 0;
        if (tid == 0) { sstar_s = 0; q_s = 0; }
        __syncthreads();
        for (int i = tid; i < NN; i += 256) {
            int s = sc[m][i];
            if (s > 0) atomicAdd(&hist[s], 1);
        }
        __syncthreads();
        int base = tid*5;
        int p = hist[base]+hist[base+1]+hist[base+2]+hist[base+3]+hist[base+4];
        int myp = p;
        #pragma unroll
        for (int off = 1; off < 64; off <<= 1) {
            int v = __shfl_down(p, off, 64);
            if (lane + off < 64) p += v;
        }
        if (lane == 0) waveTot[w] = p;
        __syncthreads();
        int suffix = p;
        for (int ww = w+1; ww < 4; ++ww) suffix += waveTot[ww];
        int running = suffix - myp;          // count in bins strictly above my range
        for (int s = base+4; s >= base; --s) {
            int c = hist[s];
            if (s >= 1 && c > 0 && running < KEEP && running + c >= KEEP) {
                sstar_s = s; q_s = KEEP - running;    // unique straddle bin
            }
            running += c;
        }
        __syncthreads();
        int sstar = sstar_s, q = q_s;

        bool eqReg[6];
        int  lowReg[6];
        #pragma unroll
        for (int c = 0; c < 6; ++c) {
            int i = c*256 + tid;
            int s = (i < NN) ? (int)sc[m][i] : 0;
            bool eq = (s > 0) && (s == sstar);
            unsigned long long bal = __ballot(eq);
            if (lane == 0) cnt6[c][w] = (int)__popcll(bal);
            eqReg[c]  = eq;
            lowReg[c] = (int)__popcll(bal & ((1ull << lane) - 1ull));
        }
        __syncthreads();
        int cum = 0;
        #pragma unroll
        for (int c = 0; c < 6; ++c) {
            int preC = cum;
            for (int ww = 0; ww < w; ++ww) preC += cnt6[c][ww];
            int E = preC + lowReg[c];       // global index-order rank among ties
            int i = c*256 + tid;
            if (i < NN) {
                int s = (int)sc[m][i];
                bool keep = (s > 0) && (s > sstar || (eqReg[c] && E < q));
                kp[m][i] = keep ? 1 : 0;
            }
            cum += cnt6[c][0]+cnt6[c][1]+cnt6[c][2]+cnt6[c][3];
        }
        __syncthreads();
    }

    // ---- write enc for ALL rows (no stale-data hazard in k2) ----
    for (int i = tid; i < NN; i += 256) {
        int idx = b*NN + i;
        int e = -1;
        if (kp[0][i])      e = 0x100 | (int)labS[i];   // positive
        else if (kp[1][i]) e = 0;                      // negative: one-hot label 0
        enc[idx] = e;
    }
}

// ---------------- K2: row-owning writer — pass A pure zero-fill, pass B sparse insert ----------------
__global__ __launch_bounds__(256) void k2_rowfill(
    const int* __restrict__ enc, const float4* __restrict__ d4,
    float* __restrict__ out)
{
    int blk = blockIdx.x;
    int tid = threadIdx.x;
    float4* outq = (float4*)out;
    const float4 z = make_float4(0.f,0.f,0.f,0.f);

    // owned ranges (both quad-aligned): deltas [dqBase, +5184), labels [lqBase, +1296)
    unsigned int dqBase = (unsigned int)blk * 5184u;          // 64 rows * 81 quads
    unsigned int lqBase = 7776000u + (unsigned int)blk * 1296u; // label section as quads

    // Pass A: branch-free streaming zero-fill (no table loads, no masks)
    for (unsigned int q = tid; q < 5184u; q += 256u) outq[dqBase + q] = z;
    for (unsigned int q = tid; q < 1296u; q += 256u) outq[lqBase + q] = z;
    __syncthreads();

    // Pass B: sparse insert for the block's 64 rows
    if (tid < ROWS_PER_BLK) {
        unsigned int r = (unsigned int)blk * ROWS_PER_BLK + (unsigned int)tid;
        int e = enc[r];
        if (e >= 0) {
            int lab = e & 0xFF;
            out[DELTA_FLOATS + r*81u + (unsigned int)lab] = 1.0f;   // one-hot
            if (e & 0x100) outq[r*81u + (unsigned int)lab] = d4[r]; // delta quad (pos only)
        }
    }
}

extern "C" void kernel_launch(void* const* d_in, const int* in_sizes, int n_in,
                              void* d_out, int out_size, void* d_ws, size_t ws_size,
                              hipStream_t stream) {
    const float4* roi = (const float4*)d_in[0];   // [B,N,4] f32
    const float4* gt  = (const float4*)d_in[1];   // [B,M,4] f32
    const int* gtl  = (const int*)d_in[2];        // [B,M]
    const int* rpos = (const int*)d_in[3];        // [B,N]
    const int* rneg = (const int*)d_in[4];        // [B,N]
    float* out = (float*)d_out;

    char* ws = (char*)d_ws;
    int*    enc = (int*)(ws);                 // 384000 B
    float4* d4  = (float4*)(ws + 384000);     // 1536000 B

    k1_select <<<NB, 256, 0, stream>>>(roi, gt, gtl, rpos, rneg, enc, d4);
    k2_rowfill<<<K2_BLOCKS, 256, 0, stream>>>(enc, d4, out);
}

// Round 12
// 49.322 us; speedup vs baseline: 1.9121x; 1.9121x over previous
//
#include <hip/hip_runtime.h>

#define NB 64
#define NN 1500
#define NM 100
#define NBINS 1280
#define KEEP 128

#define TOTALQ 9720000u        // float4 quads in out (38,880,000 floats / 4)
#define DELTA_FLOATS 31104000u
#define FILL_BLOCKS 2048
#define IOU_BLOCKS 384
#define GRID_TOTAL (FILL_BLOCKS + IOU_BLOCKS)

// ws: 0 spos[96000] int | 384000 sneg[96000] int | 768000 lbl[96000] int |
//     1152000 d4[96000] float4   (total 2,688,000 B)

// ---------------- K1: fill blocks FIRST (0..2047, unpolluted BW), IoU blocks LAST (2048..2431) ----------------
__global__ __launch_bounds__(256) void k1_fused(
    const float4* __restrict__ roi, const float4* __restrict__ gt,
    const int* __restrict__ gtl, const int* __restrict__ rpos,
    const int* __restrict__ rneg,
    int* __restrict__ spos, int* __restrict__ sneg,
    int* __restrict__ lbl, float4* __restrict__ d4,
    float4* __restrict__ outq)
{
    __shared__ float4 gtb[NM];
    __shared__ float  gta[NM];
    __shared__ int    gtlL[NM];

    int blk = blockIdx.x;
    int tid = threadIdx.x;

    if (blk < FILL_BLOCKS) {
        // pure grid-stride zero-fill — dispatched first, owns the machine
        unsigned int t = (unsigned int)blk * 256u + (unsigned int)tid;
        const unsigned int stride = FILL_BLOCKS * 256u;
        const float4 z = make_float4(0.f, 0.f, 0.f, 0.f);
        for (unsigned int q = t; q < TOTALQ; q += stride) outq[q] = z;
        return;
    }

    // IoU + eager delta (runs in the backfill tail, near-idle memory system)
    int iblk = blk - FILL_BLOCKS;
    int b = iblk / 6;
    int chunk = iblk % 6;
    if (tid < NM) {
        float4 g = gt[b*NM + tid];
        gtb[tid] = g;
        gta[tid] = (g.z - g.x) * (g.w - g.y);
        gtlL[tid] = gtl[b*NM + tid];
    }
    __syncthreads();
    int n = chunk*256 + tid;
    if (n >= NN) return;
    int idx = b*NN + n;
    float4 r = roi[idx];                        // [y1,x1,y2,x2]
    float by1=r.x, bx1=r.y, by2=r.z, bx2=r.w;
    float barea = (by2-by1)*(bx2-bx1);
    float bestIoU = -1.0f; int bestIdx = 0;
    for (int m = 0; m < NM; ++m) {
        float4 g = gtb[m];
        float xt = fmaxf(bx1, g.y);
        float yt = fmaxf(by1, g.x);
        float xb = fminf(bx2, g.w);
        float yb = fminf(by2, g.z);
        float inter = fmaxf(xb-xt, 0.0f) * fmaxf(yb-yt, 0.0f);
        float uni = (barea + gta[m]) - inter;
        float iou = inter / uni;
        if (iou > bestIoU) { bestIoU = iou; bestIdx = m; }  // first-max argmax
    }
    spos[idx] = (bestIoU > 0.5f) ? rpos[idx] : 0;
    sneg[idx] = (bestIoU < 0.5f && bestIoU > 0.1f) ? rneg[idx] : 0;
    if (bestIoU > 0.5f) {
        // eager delta for every pos-eligible row (superset of the kept set)
        float4 g = gtb[bestIdx];
        float bw = bx2 - bx1, bh = by2 - by1;
        float bcx = bx1 + 0.5f*bw, bcy = by1 + 0.5f*bh;
        float gw = g.w - g.y, gh = g.z - g.x;
        float gcx = g.y + 0.5f*gw, gcy = g.x + 0.5f*gh;
        if (bw == 0.0f) bw = 0.001f;
        if (bh == 0.0f) bh = 0.001f;
        float dx  = (gw==0.0f) ? 0.0f : (gcx-bcx)/bw;
        float dy  = (gh==0.0f) ? 0.0f : (gcy-bcy)/bh;
        float dwv = (gw==0.0f) ? 0.0f : logf(gw/bw);
        float dhv = (gh==0.0f) ? 0.0f : logf(gh/bh);
        lbl[idx] = gtlL[bestIdx];
        d4[idx] = make_float4(dy/0.1f, dx/0.1f, dhv/0.2f, dwv/0.2f);
    }
}

// ---------------- K2: per-(batch,mask) register-resident top-128 select + scatter (R8, unchanged) ----------------
__global__ __launch_bounds__(256) void k2_select(
    const int* __restrict__ sposA, const int* __restrict__ snegA,
    const int* __restrict__ lbl, const float4* __restrict__ d4,
    float* __restrict__ out)
{
    __shared__ int hist[NBINS];
    __shared__ int waveTot[4];
    __shared__ int cnt6[6][4];
    __shared__ int sstar_s, q_s;

    int b = blockIdx.x >> 1;
    int msk = blockIdx.x & 1;              // 0 = pos, 1 = neg
    const int* __restrict__ src = msk ? snegA : sposA;
    int tid = threadIdx.x;
    int lane = tid & 63, w = tid >> 6;

    // register-resident scores, i = c*256+tid mapping throughout
    int sReg[6];
    #pragma unroll
    for (int c = 0; c < 6; ++c) {
        int i = c*256 + tid;
        sReg[c] = (i < NN) ? src[b*NN + i] : 0;
    }
    for (int s = tid; s < NBINS; s += 256) hist[s] = 0;
    if (tid == 0) { sstar_s = 0; q_s = 0; }
    __syncthreads();
    #pragma unroll
    for (int c = 0; c < 6; ++c) {
        int s = sReg[c];
        if (s > 0) atomicAdd(&hist[s], 1);
    }
    __syncthreads();
    // per-thread sum over 5 bins; wave shuffle suffix scan; cross-wave combine
    int base = tid*5;
    int p = hist[base]+hist[base+1]+hist[base+2]+hist[base+3]+hist[base+4];
    int myp = p;
    #pragma unroll
    for (int off = 1; off < 64; off <<= 1) {
        int v = __shfl_down(p, off, 64);
        if (lane + off < 64) p += v;
    }
    if (lane == 0) waveTot[w] = p;
    __syncthreads();
    int suffix = p;
    for (int ww = w+1; ww < 4; ++ww) suffix += waveTot[ww];
    int running = suffix - myp;          // count in bins strictly above my range
    for (int s = base+4; s >= base; --s) {
        int c = hist[s];
        if (s >= 1 && c > 0 && running < KEEP && running + c >= KEEP) {
            sstar_s = s; q_s = KEEP - running;    // unique straddle bin
        }
        running += c;
    }
    __syncthreads();
    int sstar = sstar_s, q = q_s;

    // ordered tie-scan, two passes, 1 barrier between
    bool eqReg[6];
    int  lowReg[6];
    #pragma unroll
    for (int c = 0; c < 6; ++c) {
        int s = sReg[c];
        bool eq = (s > 0) && (s == sstar);
        unsigned long long bal = __ballot(eq);
        if (lane == 0) cnt6[c][w] = (int)__popcll(bal);
        eqReg[c]  = eq;
        lowReg[c] = (int)__popcll(bal & ((1ull << lane) - 1ull));
    }
    __syncthreads();
    bool keepReg[6];
    int cum = 0;
    #pragma unroll
    for (int c = 0; c < 6; ++c) {
        int preC = cum;
        for (int ww = 0; ww < w; ++ww) preC += cnt6[c][ww];
        int E = preC + lowReg[c];       // global index-order rank among ties
        int s = sReg[c];
        keepReg[c] = (s > 0) && (s > sstar || (eqReg[c] && E < q));
        cum += cnt6[c][0]+cnt6[c][1]+cnt6[c][2]+cnt6[c][3];
    }

    // scatter into the (already zero-filled) output
    if (msk == 0) {
        #pragma unroll
        for (int c = 0; c < 6; ++c) {
            if (keepReg[c]) {
                int idx = b*NN + c*256 + tid;
                unsigned int slot = (unsigned int)idx * 81u + (unsigned int)lbl[idx];
                reinterpret_cast<float4*>(out)[slot] = d4[idx];  // delta quad
                out[DELTA_FLOATS + slot] = 1.0f;                 // one-hot label
            }
        }
    } else {
        #pragma unroll
        for (int c = 0; c < 6; ++c) {
            if (keepReg[c])
                out[DELTA_FLOATS + (unsigned int)(b*NN + c*256 + tid) * 81u] = 1.0f; // label 0
        }
    }
}

extern "C" void kernel_launch(void* const* d_in, const int* in_sizes, int n_in,
                              void* d_out, int out_size, void* d_ws, size_t ws_size,
                              hipStream_t stream) {
    const float4* roi = (const float4*)d_in[0];   // [B,N,4] f32
    const float4* gt  = (const float4*)d_in[1];   // [B,M,4] f32
    const int* gtl  = (const int*)d_in[2];        // [B,M]
    const int* rpos = (const int*)d_in[3];        // [B,N]
    const int* rneg = (const int*)d_in[4];        // [B,N]
    float* out = (float*)d_out;

    char* ws = (char*)d_ws;
    int*    spos = (int*)(ws);                // 384000 B
    int*    sneg = (int*)(ws +  384000);      // 384000 B
    int*    lbl  = (int*)(ws +  768000);      // 384000 B
    float4* d4   = (float4*)(ws + 1152000);   // 1536000 B

    k1_fused <<<GRID_TOTAL, 256, 0, stream>>>(roi, gt, gtl, rpos, rneg,
                                              spos, sneg, lbl, d4, (float4*)out);
    k2_select<<<NB*2, 256, 0, stream>>>(spos, sneg, lbl, d4, out);
}

// Round 13
// 47.673 us; speedup vs baseline: 1.9782x; 1.0346x over previous
//
#include <hip/hip_runtime.h>

#define NB 64
#define NN 1500
#define NM 100
#define NBINS 1280
#define KEEP 128

#define DELTA_FLOATS 31104000u   // floats in delta section
#define IOU_BLOCKS 384           // 64 batches x 6 chunks

// ws: 0 spos[96000] int | 384000 sneg[96000] int | 768000 lbl[96000] int |
//     1152000 d4[96000] float4   (total 2,688,000 B)

// ---------------- K1: IoU + argmax + masked scores + eager delta (384 blocks) ----------------
__global__ __launch_bounds__(256) void k1_iou(
    const float4* __restrict__ roi, const float4* __restrict__ gt,
    const int* __restrict__ gtl, const int* __restrict__ rpos,
    const int* __restrict__ rneg,
    int* __restrict__ spos, int* __restrict__ sneg,
    int* __restrict__ lbl, float4* __restrict__ d4)
{
    __shared__ float4 gtb[NM];
    __shared__ float  gta[NM];
    __shared__ int    gtlL[NM];

    int blk = blockIdx.x;
    int tid = threadIdx.x;
    int b = blk / 6;
    int chunk = blk % 6;
    if (tid < NM) {
        float4 g = gt[b*NM + tid];
        gtb[tid] = g;
        gta[tid] = (g.z - g.x) * (g.w - g.y);   // (gy2-gy1)*(gx2-gx1)
        gtlL[tid] = gtl[b*NM + tid];
    }
    __syncthreads();
    int n = chunk*256 + tid;
    if (n >= NN) return;
    int idx = b*NN + n;
    float4 r = roi[idx];                        // [y1,x1,y2,x2]
    float by1=r.x, bx1=r.y, by2=r.z, bx2=r.w;
    float barea = (by2-by1)*(bx2-bx1);
    float bestIoU = -1.0f; int bestIdx = 0;
    for (int m = 0; m < NM; ++m) {
        float4 g = gtb[m];
        float xt = fmaxf(bx1, g.y);
        float yt = fmaxf(by1, g.x);
        float xb = fminf(bx2, g.w);
        float yb = fminf(by2, g.z);
        float inter = fmaxf(xb-xt, 0.0f) * fmaxf(yb-yt, 0.0f);
        float uni = (barea + gta[m]) - inter;
        float iou = inter / uni;
        if (iou > bestIoU) { bestIoU = iou; bestIdx = m; }  // first-max argmax
    }
    spos[idx] = (bestIoU > 0.5f) ? rpos[idx] : 0;
    sneg[idx] = (bestIoU < 0.5f && bestIoU > 0.1f) ? rneg[idx] : 0;
    if (bestIoU > 0.5f) {
        // eager delta for every pos-eligible row (superset of the kept set)
        float4 g = gtb[bestIdx];
        float bw = bx2 - bx1, bh = by2 - by1;
        float bcx = bx1 + 0.5f*bw, bcy = by1 + 0.5f*bh;
        float gw = g.w - g.y, gh = g.z - g.x;
        float gcx = g.y + 0.5f*gw, gcy = g.x + 0.5f*gh;
        if (bw == 0.0f) bw = 0.001f;
        if (bh == 0.0f) bh = 0.001f;
        float dx  = (gw==0.0f) ? 0.0f : (gcx-bcx)/bw;
        float dy  = (gh==0.0f) ? 0.0f : (gcy-bcy)/bh;
        float dwv = (gw==0.0f) ? 0.0f : logf(gw/bw);
        float dhv = (gh==0.0f) ? 0.0f : logf(gh/bh);
        lbl[idx] = gtlL[bestIdx];
        d4[idx] = make_float4(dy/0.1f, dx/0.1f, dhv/0.2f, dwv/0.2f);
    }
}

// ---------------- K2: per-(batch,mask) register-resident top-128 select + scatter (R8, unchanged) ----------------
__global__ __launch_bounds__(256) void k2_select(
    const int* __restrict__ sposA, const int* __restrict__ snegA,
    const int* __restrict__ lbl, const float4* __restrict__ d4,
    float* __restrict__ out)
{
    __shared__ int hist[NBINS];
    __shared__ int waveTot[4];
    __shared__ int cnt6[6][4];
    __shared__ int sstar_s, q_s;

    int b = blockIdx.x >> 1;
    int msk = blockIdx.x & 1;              // 0 = pos, 1 = neg
    const int* __restrict__ src = msk ? snegA : sposA;
    int tid = threadIdx.x;
    int lane = tid & 63, w = tid >> 6;

    // register-resident scores, i = c*256+tid mapping throughout
    int sReg[6];
    #pragma unroll
    for (int c = 0; c < 6; ++c) {
        int i = c*256 + tid;
        sReg[c] = (i < NN) ? src[b*NN + i] : 0;
    }
    for (int s = tid; s < NBINS; s += 256) hist[s] = 0;
    if (tid == 0) { sstar_s = 0; q_s = 0; }
    __syncthreads();
    #pragma unroll
    for (int c = 0; c < 6; ++c) {
        int s = sReg[c];
        if (s > 0) atomicAdd(&hist[s], 1);
    }
    __syncthreads();
    // per-thread sum over 5 bins; wave shuffle suffix scan; cross-wave combine
    int base = tid*5;
    int p = hist[base]+hist[base+1]+hist[base+2]+hist[base+3]+hist[base+4];
    int myp = p;
    #pragma unroll
    for (int off = 1; off < 64; off <<= 1) {
        int v = __shfl_down(p, off, 64);
        if (lane + off < 64) p += v;
    }
    if (lane == 0) waveTot[w] = p;
    __syncthreads();
    int suffix = p;
    for (int ww = w+1; ww < 4; ++ww) suffix += waveTot[ww];
    int running = suffix - myp;          // count in bins strictly above my range
    for (int s = base+4; s >= base; --s) {
        int c = hist[s];
        if (s >= 1 && c > 0 && running < KEEP && running + c >= KEEP) {
            sstar_s = s; q_s = KEEP - running;    // unique straddle bin
        }
        running += c;
    }
    __syncthreads();
    int sstar = sstar_s, q = q_s;

    // ordered tie-scan, two passes, 1 barrier between
    bool eqReg[6];
    int  lowReg[6];
    #pragma unroll
    for (int c = 0; c < 6; ++c) {
        int s = sReg[c];
        bool eq = (s > 0) && (s == sstar);
        unsigned long long bal = __ballot(eq);
        if (lane == 0) cnt6[c][w] = (int)__popcll(bal);
        eqReg[c]  = eq;
        lowReg[c] = (int)__popcll(bal & ((1ull << lane) - 1ull));
    }
    __syncthreads();
    bool keepReg[6];
    int cum = 0;
    #pragma unroll
    for (int c = 0; c < 6; ++c) {
        int preC = cum;
        for (int ww = 0; ww < w; ++ww) preC += cnt6[c][ww];
        int E = preC + lowReg[c];       // global index-order rank among ties
        int s = sReg[c];
        keepReg[c] = (s > 0) && (s > sstar || (eqReg[c] && E < q));
        cum += cnt6[c][0]+cnt6[c][1]+cnt6[c][2]+cnt6[c][3];
    }

    // scatter into the (memset-zeroed) output
    if (msk == 0) {
        #pragma unroll
        for (int c = 0; c < 6; ++c) {
            if (keepReg[c]) {
                int idx = b*NN + c*256 + tid;
                unsigned int slot = (unsigned int)idx * 81u + (unsigned int)lbl[idx];
                reinterpret_cast<float4*>(out)[slot] = d4[idx];  // delta quad
                out[DELTA_FLOATS + slot] = 1.0f;                 // one-hot label
            }
        }
    } else {
        #pragma unroll
        for (int c = 0; c < 6; ++c) {
            if (keepReg[c])
                out[DELTA_FLOATS + (unsigned int)(b*NN + c*256 + tid) * 81u] = 1.0f; // label 0
        }
    }
}

extern "C" void kernel_launch(void* const* d_in, const int* in_sizes, int n_in,
                              void* d_out, int out_size, void* d_ws, size_t ws_size,
                              hipStream_t stream) {
    const float4* roi = (const float4*)d_in[0];   // [B,N,4] f32
    const float4* gt  = (const float4*)d_in[1];   // [B,M,4] f32
    const int* gtl  = (const int*)d_in[2];        // [B,M]
    const int* rpos = (const int*)d_in[3];        // [B,N]
    const int* rneg = (const int*)d_in[4];        // [B,N]
    float* out = (float*)d_out;

    char* ws = (char*)d_ws;
    int*    spos = (int*)(ws);                // 384000 B
    int*    sneg = (int*)(ws +  384000);      // 384000 B
    int*    lbl  = (int*)(ws +  768000);      // 384000 B
    float4* d4   = (float4*)(ws + 1152000);   // 1536000 B

    // zero the whole output via the runtime's tuned blit (measured 6.5-6.9 TB/s)
    hipMemsetAsync(out, 0, (size_t)out_size * sizeof(float), stream);
    k1_iou  <<<IOU_BLOCKS, 256, 0, stream>>>(roi, gt, gtl, rpos, rneg,
                                             spos, sneg, lbl, d4);
    k2_select<<<NB*2, 256, 0, stream>>>(spos, sneg, lbl, d4, out);
}

// Round 14
// 32.190 us; speedup vs baseline: 2.9298x; 1.4810x over previous
//
#include <hip/hip_runtime.h>

#define NB 64
#define NN 1500
#define NM 100
#define NBINS 1280
#define KEEP 128

#define TOTALQ 9720000u        // float4 quads in out (38,880,000 floats / 4)
#define DELTA_FLOATS 31104000u
#define IOU_BLOCKS 384
#define FILL_BLOCKS 512        // long-running fill waves (74 iters/thread), blit-style
#define GRID_TOTAL (IOU_BLOCKS + FILL_BLOCKS)

// ws: 0 spos[96000] int | 384000 sneg[96000] int | 768000 lbl[96000] int |
//     1152000 d4[96000] float4   (total 2,688,000 B)

// ---------------- K1: IoU + eager delta (blocks 0..383) + zero-fill (blocks 384..895) ----------------
__global__ __launch_bounds__(256) void k1_fused(
    const float4* __restrict__ roi, const float4* __restrict__ gt,
    const int* __restrict__ gtl, const int* __restrict__ rpos,
    const int* __restrict__ rneg,
    int* __restrict__ spos, int* __restrict__ sneg,
    int* __restrict__ lbl, float4* __restrict__ d4,
    float4* __restrict__ outq)
{
    __shared__ float4 gtb[NM];
    __shared__ float  gta[NM];
    __shared__ int    gtlL[NM];

    int blk = blockIdx.x;
    int tid = threadIdx.x;

    if (blk < IOU_BLOCKS) {
        int b = blk / 6;
        int chunk = blk % 6;
        if (tid < NM) {
            float4 g = gt[b*NM + tid];
            gtb[tid] = g;
            gta[tid] = (g.z - g.x) * (g.w - g.y);
            gtlL[tid] = gtl[b*NM + tid];
        }
        __syncthreads();
        int n = chunk*256 + tid;
        if (n >= NN) return;
        int idx = b*NN + n;
        float4 r = roi[idx];                        // [y1,x1,y2,x2]
        float by1=r.x, bx1=r.y, by2=r.z, bx2=r.w;
        float barea = (by2-by1)*(bx2-bx1);
        float bestIoU = -1.0f; int bestIdx = 0;
        for (int m = 0; m < NM; ++m) {
            float4 g = gtb[m];
            float xt = fmaxf(bx1, g.y);
            float yt = fmaxf(by1, g.x);
            float xb = fminf(bx2, g.w);
            float yb = fminf(by2, g.z);
            float inter = fmaxf(xb-xt, 0.0f) * fmaxf(yb-yt, 0.0f);
            float uni = (barea + gta[m]) - inter;
            float iou = inter / uni;
            if (iou > bestIoU) { bestIoU = iou; bestIdx = m; }  // first-max argmax
        }
        spos[idx] = (bestIoU > 0.5f) ? rpos[idx] : 0;
        sneg[idx] = (bestIoU < 0.5f && bestIoU > 0.1f) ? rneg[idx] : 0;
        if (bestIoU > 0.5f) {
            // eager delta for every pos-eligible row (superset of the kept set)
            float4 g = gtb[bestIdx];
            float bw = bx2 - bx1, bh = by2 - by1;
            float bcx = bx1 + 0.5f*bw, bcy = by1 + 0.5f*bh;
            float gw = g.w - g.y, gh = g.z - g.x;
            float gcx = g.y + 0.5f*gw, gcy = g.x + 0.5f*gh;
            if (bw == 0.0f) bw = 0.001f;
            if (bh == 0.0f) bh = 0.001f;
            float dx  = (gw==0.0f) ? 0.0f : (gcx-bcx)/bw;
            float dy  = (gh==0.0f) ? 0.0f : (gcy-bcy)/bh;
            float dwv = (gw==0.0f) ? 0.0f : logf(gw/bw);
            float dhv = (gh==0.0f) ? 0.0f : logf(gh/bh);
            lbl[idx] = gtlL[bestIdx];
            d4[idx] = make_float4(dy/0.1f, dx/0.1f, dhv/0.2f, dwv/0.2f);
        }
        return;
    }
    // long-running grid-stride zero-fill (74 iterations/thread)
    unsigned int t = (unsigned int)(blk - IOU_BLOCKS) * 256u + (unsigned int)tid;
    const unsigned int stride = FILL_BLOCKS * 256u;
    const float4 z = make_float4(0.f, 0.f, 0.f, 0.f);
    for (unsigned int q = t; q < TOTALQ; q += stride) outq[q] = z;
}

// ---------------- K2: per-(batch,mask) register-resident top-128 select + scatter (R8, unchanged) ----------------
__global__ __launch_bounds__(256) void k2_select(
    const int* __restrict__ sposA, const int* __restrict__ snegA,
    const int* __restrict__ lbl, const float4* __restrict__ d4,
    float* __restrict__ out)
{
    __shared__ int hist[NBINS];
    __shared__ int waveTot[4];
    __shared__ int cnt6[6][4];
    __shared__ int sstar_s, q_s;

    int b = blockIdx.x >> 1;
    int msk = blockIdx.x & 1;              // 0 = pos, 1 = neg
    const int* __restrict__ src = msk ? snegA : sposA;
    int tid = threadIdx.x;
    int lane = tid & 63, w = tid >> 6;

    // register-resident scores, i = c*256+tid mapping throughout
    int sReg[6];
    #pragma unroll
    for (int c = 0; c < 6; ++c) {
        int i = c*256 + tid;
        sReg[c] = (i < NN) ? src[b*NN + i] : 0;
    }
    for (int s = tid; s < NBINS; s += 256) hist[s] = 0;
    if (tid == 0) { sstar_s = 0; q_s = 0; }
    __syncthreads();
    #pragma unroll
    for (int c = 0; c < 6; ++c) {
        int s = sReg[c];
        if (s > 0) atomicAdd(&hist[s], 1);
    }
    __syncthreads();
    // per-thread sum over 5 bins; wave shuffle suffix scan; cross-wave combine
    int base = tid*5;
    int p = hist[base]+hist[base+1]+hist[base+2]+hist[base+3]+hist[base+4];
    int myp = p;
    #pragma unroll
    for (int off = 1; off < 64; off <<= 1) {
        int v = __shfl_down(p, off, 64);
        if (lane + off < 64) p += v;
    }
    if (lane == 0) waveTot[w] = p;
    __syncthreads();
    int suffix = p;
    for (int ww = w+1; ww < 4; ++ww) suffix += waveTot[ww];
    int running = suffix - myp;          // count in bins strictly above my range
    for (int s = base+4; s >= base; --s) {
        int c = hist[s];
        if (s >= 1 && c > 0 && running < KEEP && running + c >= KEEP) {
            sstar_s = s; q_s = KEEP - running;    // unique straddle bin
        }
        running += c;
    }
    __syncthreads();
    int sstar = sstar_s, q = q_s;

    // ordered tie-scan, two passes, 1 barrier between
    bool eqReg[6];
    int  lowReg[6];
    #pragma unroll
    for (int c = 0; c < 6; ++c) {
        int s = sReg[c];
        bool eq = (s > 0) && (s == sstar);
        unsigned long long bal = __ballot(eq);
        if (lane == 0) cnt6[c][w] = (int)__popcll(bal);
        eqReg[c]  = eq;
        lowReg[c] = (int)__popcll(bal & ((1ull << lane) - 1ull));
    }
    __syncthreads();
    bool keepReg[6];
    int cum = 0;
    #pragma unroll
    for (int c = 0; c < 6; ++c) {
        int preC = cum;
        for (int ww = 0; ww < w; ++ww) preC += cnt6[c][ww];
        int E = preC + lowReg[c];       // global index-order rank among ties
        int s = sReg[c];
        keepReg[c] = (s > 0) && (s > sstar || (eqReg[c] && E < q));
        cum += cnt6[c][0]+cnt6[c][1]+cnt6[c][2]+cnt6[c][3];
    }

    // scatter into the (already zero-filled) output
    if (msk == 0) {
        #pragma unroll
        for (int c = 0; c < 6; ++c) {
            if (keepReg[c]) {
                int idx = b*NN + c*256 + tid;
                unsigned int slot = (unsigned int)idx * 81u + (unsigned int)lbl[idx];
                reinterpret_cast<float4*>(out)[slot] = d4[idx];  // delta quad
                out[DELTA_FLOATS + slot] = 1.0f;                 // one-hot label
            }
        }
    } else {
        #pragma unroll
        for (int c = 0; c < 6; ++c) {
            if (keepReg[c])
                out[DELTA_FLOATS + (unsigned int)(b*NN + c*256 + tid) * 81u] = 1.0f; // label 0
        }
    }
}

extern "C" void kernel_launch(void* const* d_in, const int* in_sizes, int n_in,
                              void* d_out, int out_size, void* d_ws, size_t ws_size,
                              hipStream_t stream) {
    const float4* roi = (const float4*)d_in[0];   // [B,N,4] f32
    const float4* gt  = (const float4*)d_in[1];   // [B,M,4] f32
    const int* gtl  = (const int*)d_in[2];        // [B,M]
    const int* rpos = (const int*)d_in[3];        // [B,N]
    const int* rneg = (const int*)d_in[4];        // [B,N]
    float* out = (float*)d_out;

    char* ws = (char*)d_ws;
    int*    spos = (int*)(ws);                // 384000 B
    int*    sneg = (int*)(ws +  384000);      // 384000 B
    int*    lbl  = (int*)(ws +  768000);      // 384000 B
    float4* d4   = (float4*)(ws + 1152000);   // 1536000 B

    k1_fused <<<GRID_TOTAL, 256, 0, stream>>>(roi, gt, gtl, rpos, rneg,
                                              spos, sneg, lbl, d4, (float4*)out);
    k2_select<<<NB*2, 256, 0, stream>>>(spos, sneg, lbl, d4, out);
}

// Round 15
// 31.698 us; speedup vs baseline: 2.9753x; 1.0155x over previous
//
#include <hip/hip_runtime.h>

#define NB 64
#define NN 1500
#define NM 100
#define NBINS 1280
#define KEEP 128

#define TOTALQ 9720000u        // float4 quads in out (38,880,000 floats / 4)
#define DELTA_FLOATS 31104000u
#define IOU_BLOCKS 384
#define FILL_BLOCKS 256        // 1 block/CU, 148 iters/thread — longest store trains
#define GRID_TOTAL (IOU_BLOCKS + FILL_BLOCKS)

// ws: 0 spos[96000] int | 384000 sneg[96000] int | 768000 lbl[96000] int |
//     1152000 d4[96000] float4   (total 2,688,000 B)

// ---------------- K1: IoU + eager delta (blocks 0..383) + zero-fill (blocks 384..639) ----------------
__global__ __launch_bounds__(256) void k1_fused(
    const float4* __restrict__ roi, const float4* __restrict__ gt,
    const int* __restrict__ gtl, const int* __restrict__ rpos,
    const int* __restrict__ rneg,
    int* __restrict__ spos, int* __restrict__ sneg,
    int* __restrict__ lbl, float4* __restrict__ d4,
    float4* __restrict__ outq)
{
    __shared__ float4 gtb[NM];
    __shared__ float  gta[NM];
    __shared__ int    gtlL[NM];

    int blk = blockIdx.x;
    int tid = threadIdx.x;

    if (blk < IOU_BLOCKS) {
        int b = blk / 6;
        int chunk = blk % 6;
        if (tid < NM) {
            float4 g = gt[b*NM + tid];
            gtb[tid] = g;
            gta[tid] = (g.z - g.x) * (g.w - g.y);
            gtlL[tid] = gtl[b*NM + tid];
        }
        __syncthreads();
        int n = chunk*256 + tid;
        if (n >= NN) return;
        int idx = b*NN + n;
        float4 r = roi[idx];                        // [y1,x1,y2,x2]
        float by1=r.x, bx1=r.y, by2=r.z, bx2=r.w;
        float barea = (by2-by1)*(bx2-bx1);
        float bestIoU = -1.0f; int bestIdx = 0;
        for (int m = 0; m < NM; ++m) {
            float4 g = gtb[m];
            float xt = fmaxf(bx1, g.y);
            float yt = fmaxf(by1, g.x);
            float xb = fminf(bx2, g.w);
            float yb = fminf(by2, g.z);
            float inter = fmaxf(xb-xt, 0.0f) * fmaxf(yb-yt, 0.0f);
            float uni = (barea + gta[m]) - inter;
            float iou = inter / uni;
            if (iou > bestIoU) { bestIoU = iou; bestIdx = m; }  // first-max argmax
        }
        spos[idx] = (bestIoU > 0.5f) ? rpos[idx] : 0;
        sneg[idx] = (bestIoU < 0.5f && bestIoU > 0.1f) ? rneg[idx] : 0;
        if (bestIoU > 0.5f) {
            // eager delta for every pos-eligible row (superset of the kept set)
            float4 g = gtb[bestIdx];
            float bw = bx2 - bx1, bh = by2 - by1;
            float bcx = bx1 + 0.5f*bw, bcy = by1 + 0.5f*bh;
            float gw = g.w - g.y, gh = g.z - g.x;
            float gcx = g.y + 0.5f*gw, gcy = g.x + 0.5f*gh;
            if (bw == 0.0f) bw = 0.001f;
            if (bh == 0.0f) bh = 0.001f;
            float dx  = (gw==0.0f) ? 0.0f : (gcx-bcx)/bw;
            float dy  = (gh==0.0f) ? 0.0f : (gcy-bcy)/bh;
            float dwv = (gw==0.0f) ? 0.0f : logf(gw/bw);
            float dhv = (gh==0.0f) ? 0.0f : logf(gh/bh);
            lbl[idx] = gtlL[bestIdx];
            d4[idx] = make_float4(dy/0.1f, dx/0.1f, dhv/0.2f, dwv/0.2f);
        }
        return;
    }
    // long-running grid-stride zero-fill (148 iterations/thread)
    unsigned int t = (unsigned int)(blk - IOU_BLOCKS) * 256u + (unsigned int)tid;
    const unsigned int stride = FILL_BLOCKS * 256u;
    const float4 z = make_float4(0.f, 0.f, 0.f, 0.f);
    for (unsigned int q = t; q < TOTALQ; q += stride) outq[q] = z;
}

// ---------------- K2: per-(batch,mask) register-resident top-128 select + scatter (unchanged) ----------------
__global__ __launch_bounds__(256) void k2_select(
    const int* __restrict__ sposA, const int* __restrict__ snegA,
    const int* __restrict__ lbl, const float4* __restrict__ d4,
    float* __restrict__ out)
{
    __shared__ int hist[NBINS];
    __shared__ int waveTot[4];
    __shared__ int cnt6[6][4];
    __shared__ int sstar_s, q_s;

    int b = blockIdx.x >> 1;
    int msk = blockIdx.x & 1;              // 0 = pos, 1 = neg
    const int* __restrict__ src = msk ? snegA : sposA;
    int tid = threadIdx.x;
    int lane = tid & 63, w = tid >> 6;

    // register-resident scores, i = c*256+tid mapping throughout
    int sReg[6];
    #pragma unroll
    for (int c = 0; c < 6; ++c) {
        int i = c*256 + tid;
        sReg[c] = (i < NN) ? src[b*NN + i] : 0;
    }
    for (int s = tid; s < NBINS; s += 256) hist[s] = 0;
    if (tid == 0) { sstar_s = 0; q_s = 0; }
    __syncthreads();
    #pragma unroll
    for (int c = 0; c < 6; ++c) {
        int s = sReg[c];
        if (s > 0) atomicAdd(&hist[s], 1);
    }
    __syncthreads();
    // per-thread sum over 5 bins; wave shuffle suffix scan; cross-wave combine
    int base = tid*5;
    int p = hist[base]+hist[base+1]+hist[base+2]+hist[base+3]+hist[base+4];
    int myp = p;
    #pragma unroll
    for (int off = 1; off < 64; off <<= 1) {
        int v = __shfl_down(p, off, 64);
        if (lane + off < 64) p += v;
    }
    if (lane == 0) waveTot[w] = p;
    __syncthreads();
    int suffix = p;
    for (int ww = w+1; ww < 4; ++ww) suffix += waveTot[ww];
    int running = suffix - myp;          // count in bins strictly above my range
    for (int s = base+4; s >= base; --s) {
        int c = hist[s];
        if (s >= 1 && c > 0 && running < KEEP && running + c >= KEEP) {
            sstar_s = s; q_s = KEEP - running;    // unique straddle bin
        }
        running += c;
    }
    __syncthreads();
    int sstar = sstar_s, q = q_s;

    // ordered tie-scan, two passes, 1 barrier between
    bool eqReg[6];
    int  lowReg[6];
    #pragma unroll
    for (int c = 0; c < 6; ++c) {
        int s = sReg[c];
        bool eq = (s > 0) && (s == sstar);
        unsigned long long bal = __ballot(eq);
        if (lane == 0) cnt6[c][w] = (int)__popcll(bal);
        eqReg[c]  = eq;
        lowReg[c] = (int)__popcll(bal & ((1ull << lane) - 1ull));
    }
    __syncthreads();
    bool keepReg[6];
    int cum = 0;
    #pragma unroll
    for (int c = 0; c < 6; ++c) {
        int preC = cum;
        for (int ww = 0; ww < w; ++ww) preC += cnt6[c][ww];
        int E = preC + lowReg[c];       // global index-order rank among ties
        int s = sReg[c];
        keepReg[c] = (s > 0) && (s > sstar || (eqReg[c] && E < q));
        cum += cnt6[c][0]+cnt6[c][1]+cnt6[c][2]+cnt6[c][3];
    }

    // scatter into the (already zero-filled) output
    if (msk == 0) {
        #pragma unroll
        for (int c = 0; c < 6; ++c) {
            if (keepReg[c]) {
                int idx = b*NN + c*256 + tid;
                unsigned int slot = (unsigned int)idx * 81u + (unsigned int)lbl[idx];
                reinterpret_cast<float4*>(out)[slot] = d4[idx];  // delta quad
                out[DELTA_FLOATS + slot] = 1.0f;                 // one-hot label
            }
        }
    } else {
        #pragma unroll
        for (int c = 0; c < 6; ++c) {
            if (keepReg[c])
                out[DELTA_FLOATS + (unsigned int)(b*NN + c*256 + tid) * 81u] = 1.0f; // label 0
        }
    }
}

extern "C" void kernel_launch(void* const* d_in, const int* in_sizes, int n_in,
                              void* d_out, int out_size, void* d_ws, size_t ws_size,
                              hipStream_t stream) {
    const float4* roi = (const float4*)d_in[0];   // [B,N,4] f32
    const float4* gt  = (const float4*)d_in[1];   // [B,M,4] f32
    const int* gtl  = (const int*)d_in[2];        // [B,M]
    const int* rpos = (const int*)d_in[3];        // [B,N]
    const int* rneg = (const int*)d_in[4];        // [B,N]
    float* out = (float*)d_out;

    char* ws = (char*)d_ws;
    int*    spos = (int*)(ws);                // 384000 B
    int*    sneg = (int*)(ws +  384000);      // 384000 B
    int*    lbl  = (int*)(ws +  768000);      // 384000 B
    float4* d4   = (float4*)(ws + 1152000);   // 1536000 B

    k1_fused <<<GRID_TOTAL, 256, 0, stream>>>(roi, gt, gtl, rpos, rneg,
                                              spos, sneg, lbl, d4, (float4*)out);
    k2_select<<<NB*2, 256, 0, stream>>>(spos, sneg, lbl, d4, out);
}